// Round 11
// baseline (104.372 us; speedup 1.0000x reference)
//
#include <hip/hip_runtime.h>
#include <math.h>

// VQ quantizer: x [512,256,12] fp32, codebook [512,12] fp32.
// Outputs (concat fp32): quantized_st [512*256*12], indices-as-float [512*256], loss [1].
//
// R18 = R17 resubmitted verbatim (R17's bench was an infra failure: "MI355X
// container failed twice" -- no compile/correctness/perf signal).
//
// R17 theory: cross-round table: R7 LDS 45.2 | R9 VMEM-uniform ~40 (best;
// fell below the 41us harness fill in top-5) | R10 SMEM-asm 46.2 | R11
// readlane 46.4 | R16 SMEM-asm @67% occ 47.7. The wall ignores occupancy
// (18->67%) and path -- EXCEPT R9, whose "failed SGPR promotion" was actually
// compiler-scheduled uniform-address VMEM float4 loads (64B L1 lines, deep
// vmcnt pipelining, no drains, no fan-out toll). R9's deficit was its 35%
// delivered occupancy; R16 proved TPB=256/TPT=1/2048-block geometry delivers
// 66-69%. R17 = R9's load path (pure C++, NO asm) x R16's geometry:
//   KSPLIT=4 waves x 128-code chunks, TPT=1, 2048 blocks, VGPR ~50 (<=64 tier
//   => 8 waves/SIMD, grid-supplied 32 waves/CU). 2-code double buffer in C++;
//   the compiler inserts counted vmcnt (its strength, per guide G7). Per-CU
//   L1 service ~128cy/code-round < 272cy VALU -> not a bottleneck.
// Exact score chain (R1-R16) untouched. Pad row 512 absorbs tail prefetch
// (R9-validated). No atomics: per-block partials + reduce kernel.
namespace {
constexpr int KCB   = 512;
constexpr int DIM   = 12;
constexpr int NTOK  = 512 * 256;       // 131072
constexpr int QSIZE = NTOK * DIM;      // 1572864
constexpr int KSPLIT = 4;              // waves per block == K chunks
constexpr int KCHUNK = KCB / KSPLIT;   // 128 codes per wave
constexpr int TPB    = 256;            // 4 waves, 64 tokens/block (TPT=1)
constexpr int NBLK   = NTOK / 64;      // 2048 blocks
constexpr int ROWF   = 16;             // packed row: w[12], w2, pad[3] (64 B)
constexpr int PARTIALS_OFF = 16384;    // float offset of partials in ws

// u64 (monotone(score), k) unsigned-min == exact lexicographic
// first-occurrence argmin (validated R2-R16).
__device__ inline unsigned long long mkkey(float v, int k) {
    unsigned su = __float_as_uint(v);
    su = (su & 0x80000000u) ? ~su : (su | 0x80000000u);
    return ((unsigned long long)su << 32) | (unsigned)k;
}

// Pack codebook into 64 B rows [w0..w11, w2, 0,0,0] (w2 = EXACT fmaf chain,
// same rounding as R1-R16). Row 512 = zeros (tail-prefetch pad, never scored).
__global__ __launch_bounds__(256) void pack_cb(const float* __restrict__ cb,
                                               float* __restrict__ pk) {
    int k = blockIdx.x * blockDim.x + threadIdx.x;
    if (k >= KCB) return;
    float w[DIM];
#pragma unroll
    for (int d = 0; d < DIM; ++d) w[d] = cb[k * DIM + d];
    float w2 = 0.f;
#pragma unroll
    for (int d = 0; d < DIM; ++d) w2 = fmaf(w[d], w[d], w2);
#pragma unroll
    for (int d = 0; d < DIM; ++d) pk[k * ROWF + d] = w[d];
    pk[k * ROWF + 12] = w2;
    pk[k * ROWF + 13] = 0.f; pk[k * ROWF + 14] = 0.f; pk[k * ROWF + 15] = 0.f;
    if (k == KCB - 1) {
#pragma unroll
        for (int d = 0; d < ROWF; ++d) pk[KCB * ROWF + d] = 0.f;
    }
}

// EXACT score sequence validated R1-R16. Do not reorder. TPT=1.
#define SCORE_CODE(C0, C1, C2, W2K, KIDX)                                    \
    {                                                                        \
        const int kq_ = (KIDX);                                              \
        float xw = 0.f;                                                      \
        xw = fmaf(xs[0],  (C0).x, xw);                                       \
        xw = fmaf(xs[1],  (C0).y, xw);                                       \
        xw = fmaf(xs[2],  (C0).z, xw);                                       \
        xw = fmaf(xs[3],  (C0).w, xw);                                       \
        xw = fmaf(xs[4],  (C1).x, xw);                                       \
        xw = fmaf(xs[5],  (C1).y, xw);                                       \
        xw = fmaf(xs[6],  (C1).z, xw);                                       \
        xw = fmaf(xs[7],  (C1).w, xw);                                       \
        xw = fmaf(xs[8],  (C2).x, xw);                                       \
        xw = fmaf(xs[9],  (C2).y, xw);                                       \
        xw = fmaf(xs[10], (C2).z, xw);                                       \
        xw = fmaf(xs[11], (C2).w, xw);                                       \
        float dq = fmaf(-2.f, xw, x2) + (W2K);                               \
        bool cq = dq < best;         /* strict < => first occurrence */      \
        best = cq ? dq : best;                                               \
        bi   = cq ? kq_ : bi;                                                \
    }

// Block = 64 tokens x 4 K-chunks (wave w scans codes [w*128,(w+1)*128)).
// Codebook rows: uniform-address VMEM float4 (L1-resident after first touch),
// compiler-pipelined. LDS only for the 2 KB cross-wave key reduce.
__global__ __launch_bounds__(256, 4) void vq_main(const float* __restrict__ x,
                                                  const float* __restrict__ cb,
                                                  const float* __restrict__ pk,
                                                  float* __restrict__ out,
                                                  float* __restrict__ partials) {
    __shared__ unsigned long long keys[KSPLIT * 64];   // 2 KB
    const int tid  = threadIdx.x;
    const int lane = tid & 63;
    const int w = __builtin_amdgcn_readfirstlane(tid >> 6);  // K-chunk id
    const int tok = blockIdx.x * 64 + lane;   // all 4 waves share these 64 tokens

    // this thread's token (48 B row, 16B-aligned)
    float xs[DIM];
    float x2;
    {
        const float4* xp = (const float4*)(x + (size_t)tok * DIM);
        float4 a0 = xp[0], a1 = xp[1], a2 = xp[2];
        xs[0] = a0.x; xs[1] = a0.y; xs[2]  = a0.z; xs[3]  = a0.w;
        xs[4] = a1.x; xs[5] = a1.y; xs[6]  = a1.z; xs[7]  = a1.w;
        xs[8] = a2.x; xs[9] = a2.y; xs[10] = a2.z; xs[11] = a2.w;
        float t2 = 0.f;
#pragma unroll
        for (int d = 0; d < DIM; ++d) t2 = fmaf(xs[d], xs[d], t2);
        x2 = t2;
    }

    float best = INFINITY;
    int   bi = 0;

    const int k0 = w * KCHUNK;
    const float* cw = pk + (size_t)k0 * ROWF;   // wave-uniform base

    // ---- 2-code double buffer, uniform VMEM loads, compiler-scheduled ----
    float4 A0, A1, A2; float w2A;
    float4 B0, B1, B2; float w2B;
    A0 = *(const float4*)(cw + 0);
    A1 = *(const float4*)(cw + 4);
    A2 = *(const float4*)(cw + 8);
    w2A = cw[12];
#pragma unroll 4
    for (int kk = 0; kk < KCHUNK; kk += 2) {
        {   // prefetch odd code kk+1 into B (flies under A's score window)
            const float* c = cw + (size_t)(kk + 1) * ROWF;
            B0 = *(const float4*)(c + 0);
            B1 = *(const float4*)(c + 4);
            B2 = *(const float4*)(c + 8);
            w2B = c[12];
        }
        SCORE_CODE(A0, A1, A2, w2A, k0 + kk);
        {   // prefetch next even code kk+2 into A (last iter for the last
            // chunk reads pad row 512: in-bounds, loaded, never scored)
            const float* c = cw + (size_t)(kk + 2) * ROWF;
            A0 = *(const float4*)(c + 0);
            A1 = *(const float4*)(c + 4);
            A2 = *(const float4*)(c + 8);
            w2A = c[12];
        }
        SCORE_CODE(B0, B1, B2, w2B, k0 + kk + 1);
    }

    // cross-wave argmin via u64 keys in LDS (global code ids 0..511)
    keys[w * 64 + lane] = mkkey(best, bi);
    __syncthreads();

    // wave 0 finalizes (it holds the same xs for these 64 tokens)
    if (tid < 64) {
        unsigned long long m = keys[lane];
#pragma unroll
        for (int r = 1; r < KSPLIT; ++r) {
            unsigned long long v = keys[r * 64 + lane];
            m = v < m ? v : m;
        }
        const int bid = (int)(m & 0xffffffffULL);
        unsigned eu = (unsigned)(m >> 32);
        unsigned orig = (eu & 0x80000000u) ? (eu ^ 0x80000000u) : ~eu;
        const float bsc = __uint_as_float(orig);

        const float4* wrow = (const float4*)(cb + (size_t)bid * DIM);
        float4 q0 = wrow[0], q1 = wrow[1], q2 = wrow[2];
        float qs[DIM] = {q0.x, q0.y, q0.z, q0.w, q1.x, q1.y, q1.z, q1.w,
                         q2.x, q2.y, q2.z, q2.w};

        float4* qo = (float4*)(out + (size_t)tok * DIM);
        float4 r0, r1, r2;
        r0.x = xs[0] + (qs[0] - xs[0]);    r0.y = xs[1] + (qs[1] - xs[1]);
        r0.z = xs[2] + (qs[2] - xs[2]);    r0.w = xs[3] + (qs[3] - xs[3]);
        r1.x = xs[4] + (qs[4] - xs[4]);    r1.y = xs[5] + (qs[5] - xs[5]);
        r1.z = xs[6] + (qs[6] - xs[6]);    r1.w = xs[7] + (qs[7] - xs[7]);
        r2.x = xs[8] + (qs[8] - xs[8]);    r2.y = xs[9] + (qs[9] - xs[9]);
        r2.z = xs[10] + (qs[10] - xs[10]); r2.w = xs[11] + (qs[11] - xs[11]);
        qo[0] = r0; qo[1] = r1; qo[2] = r2;

        out[QSIZE + tok] = (float)bid;

        // loss partial: sum_d(q-x)^2 == best score (~1e-8 rel; thr ~2%).
        float ls = bsc * (1.25f / (float)QSIZE);
#pragma unroll
        for (int off = 32; off > 0; off >>= 1) ls += __shfl_down(ls, off);
        if (lane == 0) partials[blockIdx.x] = ls;
    }
}

// 2048 partials -> loss, single block, no atomics (stream-ordered after
// vq_main; re-runs on every replay).
__global__ __launch_bounds__(512) void reduce_loss(const float* __restrict__ partials,
                                                   float* __restrict__ out) {
    __shared__ float r[8];
    float v = (partials[threadIdx.x]        + partials[threadIdx.x + 512])
            + (partials[threadIdx.x + 1024] + partials[threadIdx.x + 1536]);
#pragma unroll
    for (int off = 32; off > 0; off >>= 1) v += __shfl_down(v, off);
    if ((threadIdx.x & 63) == 0) r[threadIdx.x >> 6] = v;
    __syncthreads();
    if (threadIdx.x == 0) {
        float t = 0.f;
#pragma unroll
        for (int i = 0; i < 8; ++i) t += r[i];
        out[QSIZE + NTOK] = t;
    }
}
} // namespace

extern "C" void kernel_launch(void* const* d_in, const int* in_sizes, int n_in,
                              void* d_out, int out_size, void* d_ws, size_t ws_size,
                              hipStream_t stream) {
    const float* x  = (const float*)d_in[0];
    const float* cb = (const float*)d_in[1];
    float* out = (float*)d_out;
    float* pk  = (float*)d_ws;                      // packed codebook (513 rows)
    float* partials = (float*)d_ws + PARTIALS_OFF;  // 2048 block partials

    pack_cb<<<2, 256, 0, stream>>>(cb, pk);
    vq_main<<<NBLK, TPB, 0, stream>>>(x, cb, pk, out, partials);
    reduce_loss<<<1, 512, 0, stream>>>(partials, out);
}